// Round 17
// baseline (123.929 us; speedup 1.0000x reference)
//
#include <hip/hip_runtime.h>

#define DIM 1024
#define HID 512
#define NE 8
#define T_TOK 4096
#define BMPAD 128
#define PAD_ROUTED (T_TOK*2 + NE*BMPAD)     // 9216
#define SHARED_BASE PAD_ROUTED              // 9216
#define TOTAL_SLOTS (SHARED_BASE + T_TOK)   // 13312
#define NRT 104                             // max row-tiles: <=72 routed + 32 shared

// meta layout: [26] routed_end, [32..] rt table (e,base)*NRT
#define M_REND 26
#define M_RT 32

// k_front block split
#define FRONT_GATE 256
#define FRONT_CONV 2048
// gemm1 grid: 832 gemm blocks + 128 w2-conv blocks
#define G1_BLOCKS 832
#define W2CONV_BLOCKS 128

typedef __attribute__((ext_vector_type(4))) float f32x4;
typedef __attribute__((ext_vector_type(8))) short s16x8;

__device__ __forceinline__ unsigned short f2bf(float f) {
    union { float f; unsigned int u; } v; v.f = f;
    unsigned int u = v.u;
    u += 0x7fffu + ((u >> 16) & 1u);   // RNE
    return (unsigned short)(u >> 16);
}
__device__ __forceinline__ float bf2f(unsigned short s) {
    union { unsigned int u; float f; } v; v.u = ((unsigned int)s) << 16;
    return v.f;
}

// async global(16B/lane) -> LDS (wave-uniform base + lane*16); global src may be per-lane
__device__ __forceinline__ void gload_lds16(const void* g, void* lds) {
    __builtin_amdgcn_global_load_lds(
        (const __attribute__((address_space(1))) unsigned int*)g,
        (__attribute__((address_space(3))) unsigned int*)lds, 16, 0, 0);
}

__device__ __forceinline__ unsigned long long pack4(f32x4 v) {
    unsigned long long o = 0;
    o |= (unsigned long long)f2bf(v[0]);
    o |= (unsigned long long)f2bf(v[1]) << 16;
    o |= (unsigned long long)f2bf(v[2]) << 32;
    o |= (unsigned long long)f2bf(v[3]) << 48;
    return o;
}

// ---------------- front: gate (blocks 0..255, no LDS) || conv w1/w3 + x (blocks 256..2303) ----------------
__global__ __launch_bounds__(256) void k_front(const float* __restrict__ x,
                                               const float* __restrict__ gw,
                                               const float* __restrict__ w1,
                                               const float* __restrict__ sw1,
                                               const float* __restrict__ w3,
                                               const float* __restrict__ sw3,
                                               unsigned short* __restrict__ wdst,
                                               unsigned short* __restrict__ xb,
                                               int* __restrict__ top_e,
                                               float* __restrict__ top_s) {
    int bid = blockIdx.x, tid = threadIdx.x;
    if (bid >= FRONT_GATE) {
        const long E0 = (long)NE * HID * DIM;   // 4194304
        const long S0 = E0;
        const long S1 = S0 + HID * DIM;
        const long S2 = S1 + E0;
        const long S3 = S2 + HID * DIM;         // 9437184
        const long TOT = S3 + (long)T_TOK * DIM; // 13631488
        long stride = (long)FRONT_CONV * 256 * 4;
        for (long i = ((long)(bid - FRONT_GATE) * 256 + tid) * 4; i < TOT; i += stride) {
            const float* src; unsigned short* dst; long off;
            if (i < S3) {
                dst = wdst + i;
                if      (i < S0) { src = w1;  off = i; }
                else if (i < S1) { src = sw1; off = i - S0; }
                else if (i < S2) { src = w3;  off = i - S1; }
                else             { src = sw3; off = i - S2; }
            } else { src = x; off = i - S3; dst = xb + off; }
            *(unsigned long long*)dst = pack4(*(const f32x4*)&src[off]);
        }
        return;
    }
    // ---- gate: 16 tokens per block, gw in registers ----
    int wv = tid >> 6, lane = tid & 63;
    f32x4 gwr[4][NE];
#pragma unroll
    for (int j0 = 0; j0 < 4; j0++) {
        int j = j0 * 64 + lane;
#pragma unroll
        for (int e = 0; e < NE; e++)
            gwr[j0][e] = *(const f32x4*)&gw[e * DIM + j * 4];
    }
    int t0 = bid * 16 + wv * 4;
    for (int tt = 0; tt < 4; tt++) {
        int t = t0 + tt;
        float p[NE];
#pragma unroll
        for (int e = 0; e < NE; e++) p[e] = 0.f;
        const f32x4* xr = (const f32x4*)(x + (size_t)t * DIM);
#pragma unroll
        for (int j0 = 0; j0 < 4; j0++) {
            f32x4 xv = xr[j0 * 64 + lane];
#pragma unroll
            for (int e = 0; e < NE; e++) {
                f32x4 wv4 = gwr[j0][e];
                p[e] += xv[0] * wv4[0] + xv[1] * wv4[1] + xv[2] * wv4[2] + xv[3] * wv4[3];
            }
        }
#pragma unroll
        for (int e = 0; e < NE; e++) {
            float v = p[e];
            for (int off = 32; off; off >>= 1) v += __shfl_xor(v, off, 64);
            p[e] = v;
        }
        if (lane == 0) {
            float s[NE];
#pragma unroll
            for (int e = 0; e < NE; e++) s[e] = 1.f / (1.f + expf(-p[e]));
            int e0 = 0;
#pragma unroll
            for (int e = 1; e < NE; e++) if (s[e] > s[e0]) e0 = e;
            int e1 = (e0 == 0) ? 1 : 0;
#pragma unroll
            for (int e = 0; e < NE; e++) if (e != e0 && s[e] > s[e1]) e1 = e;
            top_e[t * 2 + 0] = e0;  top_e[t * 2 + 1] = e1;
            top_s[t * 2 + 0] = s[e0]; top_s[t * 2 + 1] = s[e1];
        }
    }
}

// ---------------- route: single-block counting sort, wave-parallel scan ----------------
__global__ __launch_bounds__(256) void k_route(const int* __restrict__ top_e,
                                               const float* __restrict__ top_s,
                                               int* __restrict__ meta,
                                               int* __restrict__ slot_of,
                                               int* __restrict__ row_tok,
                                               float* __restrict__ row_sc) {
    __shared__ int lcnt[256][9];
    __shared__ int cntS[NE], poffS[NE], padS[NE];
    int tid = threadIdx.x;
    int base = tid * 32;

    int c0=0,c1=0,c2=0,c3=0,c4=0,c5=0,c6=0,c7=0;
    for (int i = 0; i < 32; i++) {
        int e = top_e[base + i];
        c0 += (e==0); c1 += (e==1); c2 += (e==2); c3 += (e==3);
        c4 += (e==4); c5 += (e==5); c6 += (e==6); c7 += (e==7);
    }
    lcnt[tid][0]=c0; lcnt[tid][1]=c1; lcnt[tid][2]=c2; lcnt[tid][3]=c3;
    lcnt[tid][4]=c4; lcnt[tid][5]=c5; lcnt[tid][6]=c6; lcnt[tid][7]=c7;
    __syncthreads();
    {
        int e = tid >> 5, l = tid & 31;
        int tmp[8], s = 0;
#pragma unroll
        for (int k = 0; k < 8; k++) { tmp[k] = lcnt[l * 8 + k][e]; s += tmp[k]; }
        int inc = s;
#pragma unroll
        for (int off = 1; off < 32; off <<= 1) {
            int v = __shfl_up(inc, off, 32);
            if (l >= off) inc += v;
        }
        int run = inc - s;
        if (l == 31) cntS[e] = inc;
#pragma unroll
        for (int k = 0; k < 8; k++) { lcnt[l * 8 + k][e] = run; run += tmp[k]; }
    }
    __syncthreads();
    if (tid == 0) {
        int off = 0, rt = 0;
        for (int e = 0; e < NE; e++) {
            poffS[e] = off;
            int pad = ((cntS[e] + BMPAD - 1) / BMPAD) * BMPAD;
            padS[e] = pad;
            for (int b = 0; b * BMPAD < pad; b++) {
                meta[M_RT + rt * 2] = e;
                meta[M_RT + rt * 2 + 1] = off + b * BMPAD;
                rt++;
            }
            off += pad;
        }
        meta[M_REND] = off;
        for (int b = 0; b < T_TOK / BMPAD; b++) {
            meta[M_RT + rt * 2] = NE;
            meta[M_RT + rt * 2 + 1] = SHARED_BASE + b * BMPAD;
            rt++;
        }
        for (; rt < NRT; rt++) { meta[M_RT + rt * 2] = -1; meta[M_RT + rt * 2 + 1] = 0; }
    }
    __syncthreads();
    int p0 = poffS[0] + lcnt[tid][0], p1 = poffS[1] + lcnt[tid][1];
    int p2 = poffS[2] + lcnt[tid][2], p3 = poffS[3] + lcnt[tid][3];
    int p4 = poffS[4] + lcnt[tid][4], p5 = poffS[5] + lcnt[tid][5];
    int p6 = poffS[6] + lcnt[tid][6], p7 = poffS[7] + lcnt[tid][7];
    for (int i = 0; i < 32; i++) {
        int p = base + i;
        int e = top_e[p];
        int slot = 0;
        slot = (e==0) ? p0 : slot;  p0 += (e==0);
        slot = (e==1) ? p1 : slot;  p1 += (e==1);
        slot = (e==2) ? p2 : slot;  p2 += (e==2);
        slot = (e==3) ? p3 : slot;  p3 += (e==3);
        slot = (e==4) ? p4 : slot;  p4 += (e==4);
        slot = (e==5) ? p5 : slot;  p5 += (e==5);
        slot = (e==6) ? p6 : slot;  p6 += (e==6);
        slot = (e==7) ? p7 : slot;  p7 += (e==7);
        slot_of[p] = slot;
        row_tok[slot] = p >> 1;
        row_sc[slot] = top_s[p];
    }
    __syncthreads();
    for (int e = 0; e < NE; e++) {
        int s0 = poffS[e] + cntS[e], s1 = poffS[e] + padS[e];
        for (int i = s0 + tid; i < s1; i += 256) { row_tok[i] = 0; row_sc[i] = 0.f; }
    }
}

// ---------------- GEMM1 (blocks 0..831) || w2 conv (blocks 832..959) ----------------
__global__ __launch_bounds__(512) void k_gemm1(const unsigned short* __restrict__ xb,
                                               const unsigned short* __restrict__ w1b,
                                               const unsigned short* __restrict__ w3b,
                                               const int* __restrict__ meta,
                                               const int* __restrict__ row_tok,
                                               const float* __restrict__ row_sc,
                                               unsigned short* __restrict__ g,
                                               const float* __restrict__ w2,
                                               const float* __restrict__ sw2,
                                               unsigned short* __restrict__ w2b) {
    int flat = blockIdx.x, tid = threadIdx.x;
    if (flat >= G1_BLOCKS) {
        const long NW2 = (long)NE * DIM * HID;
        const long TOTC = NW2 + (long)DIM * HID;
        long stride = (long)W2CONV_BLOCKS * 512 * 4;
        for (long i = ((long)(flat - G1_BLOCKS) * 512 + tid) * 4; i < TOTC; i += stride) {
            const float* src = (i < NW2) ? w2 : sw2;
            long off = (i < NW2) ? i : i - NW2;
            *(unsigned long long*)&w2b[i] = pack4(*(const f32x4*)&src[off]);
        }
        return;
    }
    int work = (flat & 7) * NRT + (flat >> 3);
    int rt = work >> 3, ct = work & 7;
    int e = meta[M_RT + rt * 2];
    if (e < 0) return;
    int rowbase = meta[M_RT + rt * 2 + 1];
    int nbase = ct * 64;
    bool shared_tile = (e == NE);

    __shared__ __align__(16) unsigned short As[2][128 * 64];
    __shared__ __align__(16) unsigned short B1s[2][64 * 64];
    __shared__ __align__(16) unsigned short B3s[2][64 * 64];

    int w = tid >> 6, lane = tid & 63;
    int l15 = lane & 15, kq = lane >> 4;
    int wr = w >> 2, wc = w & 3;
    int lr = lane >> 3;
    int lcs = ((lane & 7) ^ lr) << 4;
    int rx = l15 & 7;

    // per-lane staging base pointers (hoisted, advance by k0*2 only)
    const char* asrc[2];
#pragma unroll
    for (int j = 0; j < 2; j++) {
        int slot = rowbase + j * 64 + w * 8 + lr;
        int tok = shared_tile ? (slot - SHARED_BASE) : row_tok[slot];
        asrc[j] = (const char*)xb + (size_t)tok * (DIM * 2) + lcs;
    }
    const char* b1p = (const char*)(w1b + (size_t)e * HID * DIM + (size_t)(nbase + w * 8 + lr) * DIM) + lcs;
    const char* b3p = (const char*)(w3b + (size_t)e * HID * DIM + (size_t)(nbase + w * 8 + lr) * DIM) + lcs;
    char* ldsA0 = (char*)As[0] + (w * 8) * 128;
    char* ldsA1 = (char*)As[0] + (64 + w * 8) * 128;
    char* ldsB1 = (char*)B1s[0] + (w * 8) * 128;
    char* ldsB3 = (char*)B3s[0] + (w * 8) * 128;
    const int BUFA = 128 * 64 * 2, BUFB = 64 * 64 * 2;   // bytes per buffer

    f32x4 acc1[4], acc3[4];
#pragma unroll
    for (int m = 0; m < 4; m++) {
        acc1[m] = (f32x4){0.f, 0.f, 0.f, 0.f};
        acc3[m] = (f32x4){0.f, 0.f, 0.f, 0.f};
    }

    auto STAGE = [&](int b, int k0) {
        gload_lds16(asrc[0] + k0 * 2, ldsA0 + b * BUFA);
        gload_lds16(asrc[1] + k0 * 2, ldsA1 + b * BUFA);
        gload_lds16(b1p + k0 * 2, ldsB1 + b * BUFB);
        gload_lds16(b3p + k0 * 2, ldsB3 + b * BUFB);
    };

    STAGE(0, 0);
#pragma unroll 1
    for (int t = 0; t < 16; t++) {
        int cur = t & 1;
        if (t < 15) {
            STAGE(cur ^ 1, (t + 1) * 64);
            asm volatile("s_waitcnt vmcnt(4)" ::: "memory");
        } else {
            asm volatile("s_waitcnt vmcnt(0)" ::: "memory");
        }
        __builtin_amdgcn_sched_barrier(0);
        __builtin_amdgcn_s_barrier();
        __builtin_amdgcn_sched_barrier(0);
        __builtin_amdgcn_s_setprio(1);
#pragma unroll
        for (int kk = 0; kk < 64; kk += 32) {
            int sl = kq + (kk >> 3);
            s16x8 af[4], b1f, b3f;
#pragma unroll
            for (int m = 0; m < 4; m++)
                af[m] = *(const s16x8*)&As[cur][(wr * 64 + m * 16 + l15) * 64 + ((sl ^ rx) << 3)];
            b1f = *(const s16x8*)&B1s[cur][(wc * 16 + l15) * 64 + ((sl ^ rx) << 3)];
            b3f = *(const s16x8*)&B3s[cur][(wc * 16 + l15) * 64 + ((sl ^ rx) << 3)];
#pragma unroll
            for (int m = 0; m < 4; m++) {
                acc1[m] = __builtin_amdgcn_mfma_f32_16x16x32_bf16(af[m], b1f, acc1[m], 0, 0, 0);
                acc3[m] = __builtin_amdgcn_mfma_f32_16x16x32_bf16(af[m], b3f, acc3[m], 0, 0, 0);
            }
        }
        __builtin_amdgcn_s_setprio(0);
        __builtin_amdgcn_sched_barrier(0);
        __builtin_amdgcn_s_barrier();
    }
#pragma unroll
    for (int m = 0; m < 4; m++)
#pragma unroll
        for (int i = 0; i < 4; i++) {
            int row = rowbase + wr * 64 + m * 16 + kq * 4 + i;
            float sc = shared_tile ? 1.f : row_sc[row];
            float h1 = sc * acc1[m][i], h3 = sc * acc3[m][i];
            float gv = h1 / (1.f + expf(-h1)) * h3;
            int col = nbase + wc * 16 + l15;
            g[(size_t)row * HID + col] = f2bf(gv);
        }
}

// ---------------- GEMM2: 128x128 tile, BK=64, 512 threads (8 waves), y = g W2^T ----------------
__global__ __launch_bounds__(512) void k_gemm2(const unsigned short* __restrict__ g,
                                               const unsigned short* __restrict__ w2b,
                                               const int* __restrict__ meta,
                                               unsigned short* __restrict__ y) {
    int flat = blockIdx.y * NRT + blockIdx.x;
    int work = (flat & 7) * NRT + (flat >> 3);
    int rt = work >> 3, ct = work & 7;
    int e = meta[M_RT + rt * 2];
    if (e < 0) return;
    int rowbase = meta[M_RT + rt * 2 + 1];
    int nbase = ct * 128;

    __shared__ __align__(16) unsigned short As[2][128 * 64];
    __shared__ __align__(16) unsigned short Bs[2][128 * 64];

    int tid = threadIdx.x, w = tid >> 6, lane = tid & 63;
    int l15 = lane & 15, kq = lane >> 4;
    int wr = w >> 2, wc = w & 3;
    int lr = lane >> 3;
    int lcs = ((lane & 7) ^ lr) << 4;
    int rx = l15 & 7;

    // hoisted per-lane staging pointers (2 issues each for A and B)
    const char* ap[2]; const char* bp[2];
    char* ldsA[2]; char* ldsB[2];
#pragma unroll
    for (int j = 0; j < 2; j++) {
        int r0 = j * 64 + w * 8;
        ap[j] = (const char*)(g + (size_t)(rowbase + r0 + lr) * HID) + lcs;
        bp[j] = (const char*)(w2b + (size_t)e * DIM * HID + (size_t)(nbase + r0 + lr) * HID) + lcs;
        ldsA[j] = (char*)As[0] + r0 * 128;
        ldsB[j] = (char*)Bs[0] + r0 * 128;
    }
    const int BUF = 128 * 64 * 2;

    f32x4 acc[4][2];
#pragma unroll
    for (int m = 0; m < 4; m++)
#pragma unroll
        for (int n = 0; n < 2; n++) acc[m][n] = (f32x4){0.f, 0.f, 0.f, 0.f};

    auto STAGE = [&](int b, int k0) {
#pragma unroll
        for (int j = 0; j < 2; j++) {
            gload_lds16(ap[j] + k0 * 2, ldsA[j] + b * BUF);
            gload_lds16(bp[j] + k0 * 2, ldsB[j] + b * BUF);
        }
    };

    STAGE(0, 0);
#pragma unroll 1
    for (int t = 0; t < 8; t++) {
        int cur = t & 1;
        if (t < 7) {
            STAGE(cur ^ 1, (t + 1) * 64);
            asm volatile("s_waitcnt vmcnt(4)" ::: "memory");
        } else {
            asm volatile("s_waitcnt vmcnt(0)" ::: "memory");
        }
        __builtin_amdgcn_sched_barrier(0);
        __builtin_amdgcn_s_barrier();
        __builtin_amdgcn_sched_barrier(0);
        __builtin_amdgcn_s_setprio(1);
#pragma unroll
        for (int kk = 0; kk < 64; kk += 32) {
            int sl = kq + (kk >> 3);
            s16x8 af[4], bf[2];
#pragma unroll
            for (int m = 0; m < 4; m++)
                af[m] = *(const s16x8*)&As[cur][(wr * 64 + m * 16 + l15) * 64 + ((sl ^ rx) << 3)];
#pragma unroll
            for (int n = 0; n < 2; n++)
                bf[n] = *(const s16x8*)&Bs[cur][(wc * 32 + n * 16 + l15) * 64 + ((sl ^ rx) << 3)];
#pragma unroll
            for (int m = 0; m < 4; m++)
#pragma unroll
                for (int n = 0; n < 2; n++)
                    acc[m][n] = __builtin_amdgcn_mfma_f32_16x16x32_bf16(af[m], bf[n], acc[m][n], 0, 0, 0);
        }
        __builtin_amdgcn_s_setprio(0);
        __builtin_amdgcn_sched_barrier(0);
        __builtin_amdgcn_s_barrier();
    }
#pragma unroll
    for (int m = 0; m < 4; m++)
#pragma unroll
        for (int n = 0; n < 2; n++)
#pragma unroll
            for (int i = 0; i < 4; i++) {
                int row = rowbase + wr * 64 + m * 16 + kq * 4 + i;
                int col = nbase + wc * 32 + n * 16 + l15;
                y[(size_t)row * DIM + col] = f2bf(acc[m][n][i]);
            }
}

// ---------------- combine: out[t] = y[s0]+y[s1]+y[shared+t] (fp32 out) ----------------
__global__ __launch_bounds__(256) void k_combine(const unsigned short* __restrict__ y,
                                                 const int* __restrict__ slot_of,
                                                 float* __restrict__ out) {
    int idx = blockIdx.x * 256 + threadIdx.x;
    int t = idx >> 7;
    int d = (idx & 127) << 3;
    int s0 = slot_of[2 * t], s1 = slot_of[2 * t + 1];
    s16x8 a = *(const s16x8*)&y[(size_t)s0 * DIM + d];
    s16x8 b = *(const s16x8*)&y[(size_t)s1 * DIM + d];
    s16x8 c = *(const s16x8*)&y[(size_t)(SHARED_BASE + t) * DIM + d];
    f32x4 o0, o1;
#pragma unroll
    for (int i = 0; i < 4; i++) {
        o0[i] = bf2f((unsigned short)a[i]) + bf2f((unsigned short)b[i]) + bf2f((unsigned short)c[i]);
        o1[i] = bf2f((unsigned short)a[i + 4]) + bf2f((unsigned short)b[i + 4]) + bf2f((unsigned short)c[i + 4]);
    }
    *(f32x4*)&out[(size_t)t * DIM + d + 0] = o0;
    *(f32x4*)&out[(size_t)t * DIM + d + 4] = o1;
}

extern "C" void kernel_launch(void* const* d_in, const int* in_sizes, int n_in,
                              void* d_out, int out_size, void* d_ws, size_t ws_size,
                              hipStream_t stream) {
    const float* x   = (const float*)d_in[0];
    const float* gw  = (const float*)d_in[1];
    const float* w1  = (const float*)d_in[2];
    const float* w2  = (const float*)d_in[3];
    const float* w3  = (const float*)d_in[4];
    const float* sw1 = (const float*)d_in[5];
    const float* sw2 = (const float*)d_in[6];
    const float* sw3 = (const float*)d_in[7];
    float* out = (float*)d_out;

    char* ws = (char*)d_ws;
    size_t off = 0;
    unsigned short* W1B = (unsigned short*)(ws + off); off += (size_t)9 * HID * DIM * 2;
    unsigned short* W3B = (unsigned short*)(ws + off); off += (size_t)9 * HID * DIM * 2;
    unsigned short* W2B = (unsigned short*)(ws + off); off += (size_t)9 * DIM * HID * 2;
    unsigned short* A1  = (unsigned short*)(ws + off); off += (size_t)TOTAL_SLOTS * DIM * 2;
    unsigned short* G   = (unsigned short*)(ws + off); off += (size_t)TOTAL_SLOTS * HID * 2;
    unsigned short* Y   = A1;
    unsigned short* XB  = A1 + (size_t)SHARED_BASE * DIM;
    int*   TOPE = (int*)(ws + off);   off += T_TOK * 2 * 4;
    float* TOPS = (float*)(ws + off); off += T_TOK * 2 * 4;
    int*   SLOT = (int*)(ws + off);   off += T_TOK * 2 * 4;
    int*   RTOK = (int*)(ws + off);   off += TOTAL_SLOTS * 4;
    float* RSC  = (float*)(ws + off); off += TOTAL_SLOTS * 4;
    int*   META = (int*)(ws + off);   off += 1024;

    k_front<<<FRONT_GATE + FRONT_CONV, 256, 0, stream>>>(x, gw, w1, sw1, w3, sw3,
                                                         W1B, XB, TOPE, TOPS);
    k_route<<<1, 256, 0, stream>>>(TOPE, TOPS, META, SLOT, RTOK, RSC);

    k_gemm1<<<G1_BLOCKS + W2CONV_BLOCKS, 512, 0, stream>>>(XB, W1B, W3B, META, RTOK, RSC, G,
                                                           w2, sw2, W2B);
    k_gemm2<<<dim3(NRT, 8, 1), 512, 0, stream>>>(G, W2B, META, Y);

    k_combine<<<(T_TOK * DIM / 8) / 256, 256, 0, stream>>>(Y, SLOT, out);
}

// Round 18
// 123.577 us; speedup vs baseline: 1.0029x; 1.0029x over previous
//
#include <hip/hip_runtime.h>

#define DIM 1024
#define HID 512
#define NE 8
#define T_TOK 4096
#define BMPAD 128
#define PAD_ROUTED (T_TOK*2 + NE*BMPAD)     // 9216
#define SHARED_BASE PAD_ROUTED              // 9216
#define TOTAL_SLOTS (SHARED_BASE + T_TOK)   // 13312
#define NRT 104                             // max row-tiles: <=72 routed + 32 shared

// meta layout: [26] routed_end, [32..] rt table (e,base)*NRT
#define M_REND 26
#define M_RT 32

// k_front block split
#define FRONT_GATE 256
#define FRONT_CONV 2048
// gemm1 grid: 832 gemm blocks + 128 w2-conv blocks
#define G1_BLOCKS 832
#define W2CONV_BLOCKS 128

typedef __attribute__((ext_vector_type(4))) float f32x4;
typedef __attribute__((ext_vector_type(8))) short s16x8;

__device__ __forceinline__ unsigned short f2bf(float f) {
    union { float f; unsigned int u; } v; v.f = f;
    unsigned int u = v.u;
    u += 0x7fffu + ((u >> 16) & 1u);   // RNE
    return (unsigned short)(u >> 16);
}
__device__ __forceinline__ float bf2f(unsigned short s) {
    union { unsigned int u; float f; } v; v.u = ((unsigned int)s) << 16;
    return v.f;
}

// async global(16B/lane) -> LDS (wave-uniform base + lane*16); global src may be per-lane
__device__ __forceinline__ void gload_lds16(const void* g, void* lds) {
    __builtin_amdgcn_global_load_lds(
        (const __attribute__((address_space(1))) unsigned int*)g,
        (__attribute__((address_space(3))) unsigned int*)lds, 16, 0, 0);
}

__device__ __forceinline__ unsigned long long pack4(f32x4 v) {
    unsigned long long o = 0;
    o |= (unsigned long long)f2bf(v[0]);
    o |= (unsigned long long)f2bf(v[1]) << 16;
    o |= (unsigned long long)f2bf(v[2]) << 32;
    o |= (unsigned long long)f2bf(v[3]) << 48;
    return o;
}

// ---------------- front: gate+x->bf16 (blocks 0..255) || conv w1/w3 (blocks 256..2303) ----------------
__global__ __launch_bounds__(256) void k_front(const float* __restrict__ x,
                                               const float* __restrict__ gw,
                                               const float* __restrict__ w1,
                                               const float* __restrict__ sw1,
                                               const float* __restrict__ w3,
                                               const float* __restrict__ sw3,
                                               unsigned short* __restrict__ wdst,
                                               unsigned short* __restrict__ xb,
                                               int* __restrict__ top_e,
                                               float* __restrict__ top_s) {
    int bid = blockIdx.x, tid = threadIdx.x;
    if (bid >= FRONT_GATE) {
        // ---- streaming conversion: w1|sw1|w3|sw3 (x handled by gate blocks) ----
        const long E0 = (long)NE * HID * DIM;   // 4194304
        const long S0 = E0;
        const long S1 = S0 + HID * DIM;
        const long S2 = S1 + E0;
        const long S3 = S2 + HID * DIM;         // 9437184
        long stride = (long)FRONT_CONV * 256 * 4;
        for (long i = ((long)(bid - FRONT_GATE) * 256 + tid) * 4; i < S3; i += stride) {
            const float* src; long off;
            if      (i < S0) { src = w1;  off = i; }
            else if (i < S1) { src = sw1; off = i - S0; }
            else if (i < S2) { src = w3;  off = i - S1; }
            else             { src = sw3; off = i - S2; }
            *(unsigned long long*)&wdst[i] = pack4(*(const f32x4*)&src[off]);
        }
        return;
    }
    // ---- gate: 16 tokens per block, gw in registers; also emits xb = bf16(x) ----
    int wv = tid >> 6, lane = tid & 63;
    f32x4 gwr[4][NE];
#pragma unroll
    for (int j0 = 0; j0 < 4; j0++) {
        int j = j0 * 64 + lane;
#pragma unroll
        for (int e = 0; e < NE; e++)
            gwr[j0][e] = *(const f32x4*)&gw[e * DIM + j * 4];
    }
    int t0 = bid * 16 + wv * 4;
    for (int tt = 0; tt < 4; tt++) {
        int t = t0 + tt;
        float p[NE];
#pragma unroll
        for (int e = 0; e < NE; e++) p[e] = 0.f;
        const f32x4* xr = (const f32x4*)(x + (size_t)t * DIM);
#pragma unroll
        for (int j0 = 0; j0 < 4; j0++) {
            int j = j0 * 64 + lane;
            f32x4 xv = xr[j];
            *(unsigned long long*)&xb[(size_t)t * DIM + j * 4] = pack4(xv);
#pragma unroll
            for (int e = 0; e < NE; e++) {
                f32x4 wv4 = gwr[j0][e];
                p[e] += xv[0] * wv4[0] + xv[1] * wv4[1] + xv[2] * wv4[2] + xv[3] * wv4[3];
            }
        }
#pragma unroll
        for (int e = 0; e < NE; e++) {
            float v = p[e];
            for (int off = 32; off; off >>= 1) v += __shfl_xor(v, off, 64);
            p[e] = v;
        }
        if (lane == 0) {
            float s[NE];
#pragma unroll
            for (int e = 0; e < NE; e++) s[e] = 1.f / (1.f + expf(-p[e]));
            int e0 = 0;
#pragma unroll
            for (int e = 1; e < NE; e++) if (s[e] > s[e0]) e0 = e;
            int e1 = (e0 == 0) ? 1 : 0;
#pragma unroll
            for (int e = 0; e < NE; e++) if (e != e0 && s[e] > s[e1]) e1 = e;
            top_e[t * 2 + 0] = e0;  top_e[t * 2 + 1] = e1;
            top_s[t * 2 + 0] = s[e0]; top_s[t * 2 + 1] = s[e1];
        }
    }
}

// ---------------- route: single-block counting sort, wave-parallel scan ----------------
__global__ __launch_bounds__(256) void k_route(const int* __restrict__ top_e,
                                               const float* __restrict__ top_s,
                                               int* __restrict__ meta,
                                               int* __restrict__ slot_of,
                                               int* __restrict__ row_tok,
                                               float* __restrict__ row_sc) {
    __shared__ int lcnt[256][9];
    __shared__ int cntS[NE], poffS[NE], padS[NE];
    int tid = threadIdx.x;
    int base = tid * 32;

    int c0=0,c1=0,c2=0,c3=0,c4=0,c5=0,c6=0,c7=0;
    for (int i = 0; i < 32; i++) {
        int e = top_e[base + i];
        c0 += (e==0); c1 += (e==1); c2 += (e==2); c3 += (e==3);
        c4 += (e==4); c5 += (e==5); c6 += (e==6); c7 += (e==7);
    }
    lcnt[tid][0]=c0; lcnt[tid][1]=c1; lcnt[tid][2]=c2; lcnt[tid][3]=c3;
    lcnt[tid][4]=c4; lcnt[tid][5]=c5; lcnt[tid][6]=c6; lcnt[tid][7]=c7;
    __syncthreads();
    {
        int e = tid >> 5, l = tid & 31;
        int tmp[8], s = 0;
#pragma unroll
        for (int k = 0; k < 8; k++) { tmp[k] = lcnt[l * 8 + k][e]; s += tmp[k]; }
        int inc = s;
#pragma unroll
        for (int off = 1; off < 32; off <<= 1) {
            int v = __shfl_up(inc, off, 32);
            if (l >= off) inc += v;
        }
        int run = inc - s;
        if (l == 31) cntS[e] = inc;
#pragma unroll
        for (int k = 0; k < 8; k++) { lcnt[l * 8 + k][e] = run; run += tmp[k]; }
    }
    __syncthreads();
    if (tid == 0) {
        int off = 0, rt = 0;
        for (int e = 0; e < NE; e++) {
            poffS[e] = off;
            int pad = ((cntS[e] + BMPAD - 1) / BMPAD) * BMPAD;
            padS[e] = pad;
            for (int b = 0; b * BMPAD < pad; b++) {
                meta[M_RT + rt * 2] = e;
                meta[M_RT + rt * 2 + 1] = off + b * BMPAD;
                rt++;
            }
            off += pad;
        }
        meta[M_REND] = off;
        for (int b = 0; b < T_TOK / BMPAD; b++) {
            meta[M_RT + rt * 2] = NE;
            meta[M_RT + rt * 2 + 1] = SHARED_BASE + b * BMPAD;
            rt++;
        }
        for (; rt < NRT; rt++) { meta[M_RT + rt * 2] = -1; meta[M_RT + rt * 2 + 1] = 0; }
    }
    __syncthreads();
    int p0 = poffS[0] + lcnt[tid][0], p1 = poffS[1] + lcnt[tid][1];
    int p2 = poffS[2] + lcnt[tid][2], p3 = poffS[3] + lcnt[tid][3];
    int p4 = poffS[4] + lcnt[tid][4], p5 = poffS[5] + lcnt[tid][5];
    int p6 = poffS[6] + lcnt[tid][6], p7 = poffS[7] + lcnt[tid][7];
    for (int i = 0; i < 32; i++) {
        int p = base + i;
        int e = top_e[p];
        int slot = 0;
        slot = (e==0) ? p0 : slot;  p0 += (e==0);
        slot = (e==1) ? p1 : slot;  p1 += (e==1);
        slot = (e==2) ? p2 : slot;  p2 += (e==2);
        slot = (e==3) ? p3 : slot;  p3 += (e==3);
        slot = (e==4) ? p4 : slot;  p4 += (e==4);
        slot = (e==5) ? p5 : slot;  p5 += (e==5);
        slot = (e==6) ? p6 : slot;  p6 += (e==6);
        slot = (e==7) ? p7 : slot;  p7 += (e==7);
        slot_of[p] = slot;
        row_tok[slot] = p >> 1;
        row_sc[slot] = top_s[p];
    }
    __syncthreads();
    for (int e = 0; e < NE; e++) {
        int s0 = poffS[e] + cntS[e], s1 = poffS[e] + padS[e];
        for (int i = s0 + tid; i < s1; i += 256) { row_tok[i] = 0; row_sc[i] = 0.f; }
    }
}

// ---------------- GEMM1 (blocks 0..831) || w2 conv (blocks 832..959) ----------------
__global__ __launch_bounds__(512) void k_gemm1(const unsigned short* __restrict__ xb,
                                               const unsigned short* __restrict__ w1b,
                                               const unsigned short* __restrict__ w3b,
                                               const int* __restrict__ meta,
                                               const int* __restrict__ row_tok,
                                               const float* __restrict__ row_sc,
                                               unsigned short* __restrict__ g,
                                               const float* __restrict__ w2,
                                               const float* __restrict__ sw2,
                                               unsigned short* __restrict__ w2b) {
    int flat = blockIdx.x, tid = threadIdx.x;
    if (flat >= G1_BLOCKS) {
        const long NW2 = (long)NE * DIM * HID;
        const long TOTC = NW2 + (long)DIM * HID;
        long stride = (long)W2CONV_BLOCKS * 512 * 4;
        for (long i = ((long)(flat - G1_BLOCKS) * 512 + tid) * 4; i < TOTC; i += stride) {
            const float* src = (i < NW2) ? w2 : sw2;
            long off = (i < NW2) ? i : i - NW2;
            *(unsigned long long*)&w2b[i] = pack4(*(const f32x4*)&src[off]);
        }
        return;
    }
    int work = (flat & 7) * NRT + (flat >> 3);       // bijective XCD chunking (832 = 8*104)
    int rt = work >> 3, ct = work & 7;
    int e = meta[M_RT + rt * 2];
    if (e < 0) return;
    int rowbase = meta[M_RT + rt * 2 + 1];
    int nbase = ct * 64;
    bool shared_tile = (e == NE);

    __shared__ __align__(16) unsigned short As[2][128 * 64];
    __shared__ __align__(16) unsigned short B1s[2][64 * 64];
    __shared__ __align__(16) unsigned short B3s[2][64 * 64];

    int w = tid >> 6, lane = tid & 63;
    int l15 = lane & 15, kq = lane >> 4;
    int wr = w >> 2, wc = w & 3;
    int lr = lane >> 3;
    int lcs = ((lane & 7) ^ lr) << 4;
    int rx = l15 & 7;

    const char* asrc[2];
#pragma unroll
    for (int j = 0; j < 2; j++) {
        int slot = rowbase + j * 64 + w * 8 + lr;
        int tok = shared_tile ? (slot - SHARED_BASE) : row_tok[slot];
        asrc[j] = (const char*)xb + (size_t)tok * (DIM * 2) + lcs;
    }
    const char* B1b = (const char*)(w1b + (size_t)e * HID * DIM + (size_t)nbase * DIM);
    const char* B3b = (const char*)(w3b + (size_t)e * HID * DIM + (size_t)nbase * DIM);

    f32x4 acc1[4], acc3[4];
#pragma unroll
    for (int m = 0; m < 4; m++) {
        acc1[m] = (f32x4){0.f, 0.f, 0.f, 0.f};
        acc3[m] = (f32x4){0.f, 0.f, 0.f, 0.f};
    }

    auto STAGE = [&](int b, int k0) {                 // 4 issues per wave
#pragma unroll
        for (int j = 0; j < 2; j++) {
            int r0 = j * 64 + w * 8;
            gload_lds16(asrc[j] + k0 * 2, (char*)As[b] + r0 * 128);
        }
        int r0 = w * 8;
        gload_lds16(B1b + (size_t)(r0 + lr) * (DIM * 2) + k0 * 2 + lcs,
                    (char*)B1s[b] + r0 * 128);
        gload_lds16(B3b + (size_t)(r0 + lr) * (DIM * 2) + k0 * 2 + lcs,
                    (char*)B3s[b] + r0 * 128);
    };

    STAGE(0, 0);
#pragma unroll 1
    for (int t = 0; t < 16; t++) {
        int cur = t & 1;
        if (t < 15) {
            STAGE(cur ^ 1, (t + 1) * 64);
            asm volatile("s_waitcnt vmcnt(4)" ::: "memory");
        } else {
            asm volatile("s_waitcnt vmcnt(0)" ::: "memory");
        }
        __builtin_amdgcn_sched_barrier(0);
        __builtin_amdgcn_s_barrier();
        __builtin_amdgcn_sched_barrier(0);
#pragma unroll
        for (int kk = 0; kk < 64; kk += 32) {
            int sl = kq + (kk >> 3);
            s16x8 af[4], b1f, b3f;
#pragma unroll
            for (int m = 0; m < 4; m++)
                af[m] = *(const s16x8*)&As[cur][(wr * 64 + m * 16 + l15) * 64 + ((sl ^ rx) << 3)];
            b1f = *(const s16x8*)&B1s[cur][(wc * 16 + l15) * 64 + ((sl ^ rx) << 3)];
            b3f = *(const s16x8*)&B3s[cur][(wc * 16 + l15) * 64 + ((sl ^ rx) << 3)];
#pragma unroll
            for (int m = 0; m < 4; m++) {
                acc1[m] = __builtin_amdgcn_mfma_f32_16x16x32_bf16(af[m], b1f, acc1[m], 0, 0, 0);
                acc3[m] = __builtin_amdgcn_mfma_f32_16x16x32_bf16(af[m], b3f, acc3[m], 0, 0, 0);
            }
        }
        __builtin_amdgcn_sched_barrier(0);
        __builtin_amdgcn_s_barrier();
    }
#pragma unroll
    for (int m = 0; m < 4; m++)
#pragma unroll
        for (int i = 0; i < 4; i++) {
            int row = rowbase + wr * 64 + m * 16 + kq * 4 + i;
            float sc = shared_tile ? 1.f : row_sc[row];
            float h1 = sc * acc1[m][i], h3 = sc * acc3[m][i];
            float gv = h1 / (1.f + expf(-h1)) * h3;
            int col = nbase + wc * 16 + l15;
            g[(size_t)row * HID + col] = f2bf(gv);
        }
}

// ---------------- GEMM2: 128x128 tile, BK=64, 512 threads (8 waves), y = g W2^T ----------------
__global__ __launch_bounds__(512) void k_gemm2(const unsigned short* __restrict__ g,
                                               const unsigned short* __restrict__ w2b,
                                               const int* __restrict__ meta,
                                               unsigned short* __restrict__ y) {
    int flat = blockIdx.y * NRT + blockIdx.x;
    int work = (flat & 7) * NRT + (flat >> 3);
    int rt = work >> 3, ct = work & 7;
    int e = meta[M_RT + rt * 2];
    if (e < 0) return;
    int rowbase = meta[M_RT + rt * 2 + 1];
    int nbase = ct * 128;

    __shared__ __align__(16) unsigned short As[2][128 * 64];
    __shared__ __align__(16) unsigned short Bs[2][128 * 64];

    int tid = threadIdx.x, w = tid >> 6, lane = tid & 63;
    int l15 = lane & 15, kq = lane >> 4;
    int wr = w >> 2, wc = w & 3;
    int lr = lane >> 3;
    int lcs = ((lane & 7) ^ lr) << 4;
    int rx = l15 & 7;

    const char* Ab = (const char*)(g + (size_t)rowbase * HID);
    const char* Bb = (const char*)(w2b + (size_t)e * DIM * HID + (size_t)nbase * HID);

    f32x4 acc[4][2];
#pragma unroll
    for (int m = 0; m < 4; m++)
#pragma unroll
        for (int n = 0; n < 2; n++) acc[m][n] = (f32x4){0.f, 0.f, 0.f, 0.f};

    auto STAGE = [&](int b, int k0) {
#pragma unroll
        for (int j = 0; j < 2; j++) {
            int r0 = j * 64 + w * 8;
            gload_lds16(Ab + (size_t)(r0 + lr) * (HID * 2) + k0 * 2 + lcs,
                        (char*)As[b] + r0 * 128);
            gload_lds16(Bb + (size_t)(r0 + lr) * (HID * 2) + k0 * 2 + lcs,
                        (char*)Bs[b] + r0 * 128);
        }
    };

    STAGE(0, 0);
#pragma unroll 1
    for (int t = 0; t < 8; t++) {
        int cur = t & 1;
        if (t < 7) {
            STAGE(cur ^ 1, (t + 1) * 64);
            asm volatile("s_waitcnt vmcnt(4)" ::: "memory");
        } else {
            asm volatile("s_waitcnt vmcnt(0)" ::: "memory");
        }
        __builtin_amdgcn_sched_barrier(0);
        __builtin_amdgcn_s_barrier();
        __builtin_amdgcn_sched_barrier(0);
#pragma unroll
        for (int kk = 0; kk < 64; kk += 32) {
            int sl = kq + (kk >> 3);
            s16x8 af[4], bf[2];
#pragma unroll
            for (int m = 0; m < 4; m++)
                af[m] = *(const s16x8*)&As[cur][(wr * 64 + m * 16 + l15) * 64 + ((sl ^ rx) << 3)];
#pragma unroll
            for (int n = 0; n < 2; n++)
                bf[n] = *(const s16x8*)&Bs[cur][(wc * 32 + n * 16 + l15) * 64 + ((sl ^ rx) << 3)];
#pragma unroll
            for (int m = 0; m < 4; m++)
#pragma unroll
                for (int n = 0; n < 2; n++)
                    acc[m][n] = __builtin_amdgcn_mfma_f32_16x16x32_bf16(af[m], bf[n], acc[m][n], 0, 0, 0);
        }
        __builtin_amdgcn_sched_barrier(0);
        __builtin_amdgcn_s_barrier();
    }
#pragma unroll
    for (int m = 0; m < 4; m++)
#pragma unroll
        for (int n = 0; n < 2; n++)
#pragma unroll
            for (int i = 0; i < 4; i++) {
                int row = rowbase + wr * 64 + m * 16 + kq * 4 + i;
                int col = nbase + wc * 32 + n * 16 + l15;
                y[(size_t)row * DIM + col] = f2bf(acc[m][n][i]);
            }
}

// ---------------- combine: out[t] = y[s0]+y[s1]+y[shared+t] (fp32 out) ----------------
__global__ __launch_bounds__(256) void k_combine(const unsigned short* __restrict__ y,
                                                 const int* __restrict__ slot_of,
                                                 float* __restrict__ out) {
    int idx = blockIdx.x * 256 + threadIdx.x;
    int t = idx >> 7;
    int d = (idx & 127) << 3;
    int s0 = slot_of[2 * t], s1 = slot_of[2 * t + 1];
    s16x8 a = *(const s16x8*)&y[(size_t)s0 * DIM + d];
    s16x8 b = *(const s16x8*)&y[(size_t)s1 * DIM + d];
    s16x8 c = *(const s16x8*)&y[(size_t)(SHARED_BASE + t) * DIM + d];
    f32x4 o0, o1;
#pragma unroll
    for (int i = 0; i < 4; i++) {
        o0[i] = bf2f((unsigned short)a[i]) + bf2f((unsigned short)b[i]) + bf2f((unsigned short)c[i]);
        o1[i] = bf2f((unsigned short)a[i + 4]) + bf2f((unsigned short)b[i + 4]) + bf2f((unsigned short)c[i + 4]);
    }
    *(f32x4*)&out[(size_t)t * DIM + d + 0] = o0;
    *(f32x4*)&out[(size_t)t * DIM + d + 4] = o1;
}

extern "C" void kernel_launch(void* const* d_in, const int* in_sizes, int n_in,
                              void* d_out, int out_size, void* d_ws, size_t ws_size,
                              hipStream_t stream) {
    const float* x   = (const float*)d_in[0];
    const float* gw  = (const float*)d_in[1];
    const float* w1  = (const float*)d_in[2];
    const float* w2  = (const float*)d_in[3];
    const float* w3  = (const float*)d_in[4];
    const float* sw1 = (const float*)d_in[5];
    const float* sw2 = (const float*)d_in[6];
    const float* sw3 = (const float*)d_in[7];
    float* out = (float*)d_out;

    char* ws = (char*)d_ws;
    size_t off = 0;
    unsigned short* W1B = (unsigned short*)(ws + off); off += (size_t)9 * HID * DIM * 2;
    unsigned short* W3B = (unsigned short*)(ws + off); off += (size_t)9 * HID * DIM * 2;
    unsigned short* W2B = (unsigned short*)(ws + off); off += (size_t)9 * DIM * HID * 2;
    unsigned short* A1  = (unsigned short*)(ws + off); off += (size_t)TOTAL_SLOTS * DIM * 2;
    unsigned short* G   = (unsigned short*)(ws + off); off += (size_t)TOTAL_SLOTS * HID * 2;
    unsigned short* Y   = A1;
    unsigned short* XB  = A1 + (size_t)SHARED_BASE * DIM;
    int*   TOPE = (int*)(ws + off);   off += T_TOK * 2 * 4;
    float* TOPS = (float*)(ws + off); off += T_TOK * 2 * 4;
    int*   SLOT = (int*)(ws + off);   off += T_TOK * 2 * 4;
    int*   RTOK = (int*)(ws + off);   off += TOTAL_SLOTS * 4;
    float* RSC  = (float*)(ws + off); off += TOTAL_SLOTS * 4;
    int*   META = (int*)(ws + off);   off += 1024;

    // fused front: gate (emits xb too) || w1/w3 -> bf16
    k_front<<<FRONT_GATE + FRONT_CONV, 256, 0, stream>>>(x, gw, w1, sw1, w3, sw3,
                                                         W1B, XB, TOPE, TOPS);
    k_route<<<1, 256, 0, stream>>>(TOPE, TOPS, META, SLOT, RTOK, RSC);

    // gemm1 (832 blocks) || w2 conversion (128 blocks)
    k_gemm1<<<G1_BLOCKS + W2CONV_BLOCKS, 512, 0, stream>>>(XB, W1B, W3B, META, RTOK, RSC, G,
                                                           w2, sw2, W2B);
    k_gemm2<<<dim3(NRT, 8, 1), 512, 0, stream>>>(G, W2B, META, Y);

    k_combine<<<(T_TOK * DIM / 8) / 256, 256, 0, stream>>>(Y, SLOT, out);
}

// Round 19
// 116.127 us; speedup vs baseline: 1.0672x; 1.0642x over previous
//
#include <hip/hip_runtime.h>

#define DIM 1024
#define HID 512
#define NE 8
#define T_TOK 4096
#define BMPAD 128
#define PAD_ROUTED (T_TOK*2 + NE*BMPAD)     // 9216
#define SHARED_BASE PAD_ROUTED              // 9216
#define TOTAL_SLOTS (SHARED_BASE + T_TOK)   // 13312
#define NRT 104                             // max row-tiles: <=72 routed + 32 shared

// meta layout: [26] routed_end, [32..] rt table (e,base)*NRT
#define M_REND 26
#define M_RT 32

// k_front block split
#define FRONT_GATE 256
#define FRONT_CONV 2048
// gemm1 grid: 832 gemm blocks + 128 w2-conv blocks
#define G1_BLOCKS 832
#define W2CONV_BLOCKS 128

typedef __attribute__((ext_vector_type(4))) float f32x4;
typedef __attribute__((ext_vector_type(4))) int i32x4;
typedef __attribute__((ext_vector_type(8))) short s16x8;

__device__ __forceinline__ unsigned short f2bf(float f) {
    union { float f; unsigned int u; } v; v.f = f;
    unsigned int u = v.u;
    u += 0x7fffu + ((u >> 16) & 1u);   // RNE
    return (unsigned short)(u >> 16);
}
__device__ __forceinline__ float bf2f(unsigned short s) {
    union { unsigned int u; float f; } v; v.u = ((unsigned int)s) << 16;
    return v.f;
}

// async global(16B/lane) -> LDS (wave-uniform base + lane*16); global src may be per-lane
__device__ __forceinline__ void gload_lds16(const void* g, void* lds) {
    __builtin_amdgcn_global_load_lds(
        (const __attribute__((address_space(1))) unsigned int*)g,
        (__attribute__((address_space(3))) unsigned int*)lds, 16, 0, 0);
}

__device__ __forceinline__ unsigned long long pack4(f32x4 v) {
    unsigned long long o = 0;
    o |= (unsigned long long)f2bf(v[0]);
    o |= (unsigned long long)f2bf(v[1]) << 16;
    o |= (unsigned long long)f2bf(v[2]) << 32;
    o |= (unsigned long long)f2bf(v[3]) << 48;
    return o;
}

// ---------------- front: gate+x->bf16 (blocks 0..255) || conv w1/w3 (blocks 256..2303) ----------------
__global__ __launch_bounds__(256) void k_front(const float* __restrict__ x,
                                               const float* __restrict__ gw,
                                               const float* __restrict__ w1,
                                               const float* __restrict__ sw1,
                                               const float* __restrict__ w3,
                                               const float* __restrict__ sw3,
                                               unsigned short* __restrict__ wdst,
                                               unsigned short* __restrict__ xb,
                                               int* __restrict__ top_e,
                                               float* __restrict__ top_s) {
    int bid = blockIdx.x, tid = threadIdx.x;
    if (bid >= FRONT_GATE) {
        // ---- streaming conversion: w1|sw1|w3|sw3 (x handled by gate blocks) ----
        const long E0 = (long)NE * HID * DIM;   // 4194304
        const long S0 = E0;
        const long S1 = S0 + HID * DIM;
        const long S2 = S1 + E0;
        const long S3 = S2 + HID * DIM;         // 9437184
        long stride = (long)FRONT_CONV * 256 * 4;
        for (long i = ((long)(bid - FRONT_GATE) * 256 + tid) * 4; i < S3; i += stride) {
            const float* src; long off;
            if      (i < S0) { src = w1;  off = i; }
            else if (i < S1) { src = sw1; off = i - S0; }
            else if (i < S2) { src = w3;  off = i - S1; }
            else             { src = sw3; off = i - S2; }
            *(unsigned long long*)&wdst[i] = pack4(*(const f32x4*)&src[off]);
        }
        return;
    }
    // ---- gate: 16 tokens per block, gw in registers; also emits xb = bf16(x) ----
    int wv = tid >> 6, lane = tid & 63;
    f32x4 gwr[4][NE];
#pragma unroll
    for (int j0 = 0; j0 < 4; j0++) {
        int j = j0 * 64 + lane;
#pragma unroll
        for (int e = 0; e < NE; e++)
            gwr[j0][e] = *(const f32x4*)&gw[e * DIM + j * 4];
    }
    int t0 = bid * 16 + wv * 4;
    for (int tt = 0; tt < 4; tt++) {
        int t = t0 + tt;
        float p[NE];
#pragma unroll
        for (int e = 0; e < NE; e++) p[e] = 0.f;
        const f32x4* xr = (const f32x4*)(x + (size_t)t * DIM);
#pragma unroll
        for (int j0 = 0; j0 < 4; j0++) {
            int j = j0 * 64 + lane;
            f32x4 xv = xr[j];
            *(unsigned long long*)&xb[(size_t)t * DIM + j * 4] = pack4(xv);
#pragma unroll
            for (int e = 0; e < NE; e++) {
                f32x4 wv4 = gwr[j0][e];
                p[e] += xv[0] * wv4[0] + xv[1] * wv4[1] + xv[2] * wv4[2] + xv[3] * wv4[3];
            }
        }
#pragma unroll
        for (int e = 0; e < NE; e++) {
            float v = p[e];
            for (int off = 32; off; off >>= 1) v += __shfl_xor(v, off, 64);
            p[e] = v;
        }
        if (lane == 0) {
            float s[NE];
#pragma unroll
            for (int e = 0; e < NE; e++) s[e] = 1.f / (1.f + expf(-p[e]));
            int e0 = 0;
#pragma unroll
            for (int e = 1; e < NE; e++) if (s[e] > s[e0]) e0 = e;
            int e1 = (e0 == 0) ? 1 : 0;
#pragma unroll
            for (int e = 0; e < NE; e++) if (e != e0 && s[e] > s[e1]) e1 = e;
            top_e[t * 2 + 0] = e0;  top_e[t * 2 + 1] = e1;
            top_s[t * 2 + 0] = s[e0]; top_s[t * 2 + 1] = s[e1];
        }
    }
}

// ---------------- route: single-block counting sort, wave-parallel scan, vectorized loads ----------------
__global__ __launch_bounds__(256) void k_route(const int* __restrict__ top_e,
                                               const float* __restrict__ top_s,
                                               int* __restrict__ meta,
                                               int* __restrict__ slot_of,
                                               int* __restrict__ row_tok,
                                               float* __restrict__ row_sc) {
    __shared__ int lcnt[256][9];
    __shared__ int cntS[NE], poffS[NE], padS[NE];
    int tid = threadIdx.x;
    int base = tid * 32;

    int c0=0,c1=0,c2=0,c3=0,c4=0,c5=0,c6=0,c7=0;
#pragma unroll
    for (int i = 0; i < 8; i++) {
        i32x4 ev = *(const i32x4*)&top_e[base + i * 4];
#pragma unroll
        for (int k = 0; k < 4; k++) {
            int e = ev[k];
            c0 += (e==0); c1 += (e==1); c2 += (e==2); c3 += (e==3);
            c4 += (e==4); c5 += (e==5); c6 += (e==6); c7 += (e==7);
        }
    }
    lcnt[tid][0]=c0; lcnt[tid][1]=c1; lcnt[tid][2]=c2; lcnt[tid][3]=c3;
    lcnt[tid][4]=c4; lcnt[tid][5]=c5; lcnt[tid][6]=c6; lcnt[tid][7]=c7;
    __syncthreads();
    // parallel exclusive scan per expert: 8 groups of 32 lanes
    {
        int e = tid >> 5, l = tid & 31;
        int tmp[8], s = 0;
#pragma unroll
        for (int k = 0; k < 8; k++) { tmp[k] = lcnt[l * 8 + k][e]; s += tmp[k]; }
        int inc = s;
#pragma unroll
        for (int off = 1; off < 32; off <<= 1) {
            int v = __shfl_up(inc, off, 32);
            if (l >= off) inc += v;
        }
        int run = inc - s;
        if (l == 31) cntS[e] = inc;
#pragma unroll
        for (int k = 0; k < 8; k++) { lcnt[l * 8 + k][e] = run; run += tmp[k]; }
    }
    __syncthreads();
    if (tid == 0) {
        int off = 0, rt = 0;
        for (int e = 0; e < NE; e++) {
            poffS[e] = off;
            int pad = ((cntS[e] + BMPAD - 1) / BMPAD) * BMPAD;
            padS[e] = pad;
            for (int b = 0; b * BMPAD < pad; b++) {
                meta[M_RT + rt * 2] = e;
                meta[M_RT + rt * 2 + 1] = off + b * BMPAD;
                rt++;
            }
            off += pad;
        }
        meta[M_REND] = off;
        for (int b = 0; b < T_TOK / BMPAD; b++) {
            meta[M_RT + rt * 2] = NE;
            meta[M_RT + rt * 2 + 1] = SHARED_BASE + b * BMPAD;
            rt++;
        }
        for (; rt < NRT; rt++) { meta[M_RT + rt * 2] = -1; meta[M_RT + rt * 2 + 1] = 0; }
    }
    __syncthreads();
    int p0 = poffS[0] + lcnt[tid][0], p1 = poffS[1] + lcnt[tid][1];
    int p2 = poffS[2] + lcnt[tid][2], p3 = poffS[3] + lcnt[tid][3];
    int p4 = poffS[4] + lcnt[tid][4], p5 = poffS[5] + lcnt[tid][5];
    int p6 = poffS[6] + lcnt[tid][6], p7 = poffS[7] + lcnt[tid][7];
#pragma unroll
    for (int i = 0; i < 8; i++) {
        i32x4 ev = *(const i32x4*)&top_e[base + i * 4];
        f32x4 sv = *(const f32x4*)&top_s[base + i * 4];
#pragma unroll
        for (int k = 0; k < 4; k++) {
            int p = base + i * 4 + k;
            int e = ev[k];
            int slot = 0;
            slot = (e==0) ? p0 : slot;  p0 += (e==0);
            slot = (e==1) ? p1 : slot;  p1 += (e==1);
            slot = (e==2) ? p2 : slot;  p2 += (e==2);
            slot = (e==3) ? p3 : slot;  p3 += (e==3);
            slot = (e==4) ? p4 : slot;  p4 += (e==4);
            slot = (e==5) ? p5 : slot;  p5 += (e==5);
            slot = (e==6) ? p6 : slot;  p6 += (e==6);
            slot = (e==7) ? p7 : slot;  p7 += (e==7);
            slot_of[p] = slot;
            row_tok[slot] = p >> 1;
            row_sc[slot] = sv[k];
        }
    }
    __syncthreads();
    // fill pad rows (score 0 -> zero contribution)
    for (int e = 0; e < NE; e++) {
        int s0 = poffS[e] + cntS[e], s1 = poffS[e] + padS[e];
        for (int i = s0 + tid; i < s1; i += 256) { row_tok[i] = 0; row_sc[i] = 0.f; }
    }
}

// ---------------- GEMM1 (blocks 0..831) || w2 conv (blocks 832..959) ----------------
__global__ __launch_bounds__(512) void k_gemm1(const unsigned short* __restrict__ xb,
                                               const unsigned short* __restrict__ w1b,
                                               const unsigned short* __restrict__ w3b,
                                               const int* __restrict__ meta,
                                               const int* __restrict__ row_tok,
                                               const float* __restrict__ row_sc,
                                               unsigned short* __restrict__ g,
                                               const float* __restrict__ w2,
                                               const float* __restrict__ sw2,
                                               unsigned short* __restrict__ w2b) {
    int flat = blockIdx.x, tid = threadIdx.x;
    if (flat >= G1_BLOCKS) {
        const long NW2 = (long)NE * DIM * HID;
        const long TOTC = NW2 + (long)DIM * HID;
        long stride = (long)W2CONV_BLOCKS * 512 * 4;
        for (long i = ((long)(flat - G1_BLOCKS) * 512 + tid) * 4; i < TOTC; i += stride) {
            const float* src = (i < NW2) ? w2 : sw2;
            long off = (i < NW2) ? i : i - NW2;
            *(unsigned long long*)&w2b[i] = pack4(*(const f32x4*)&src[off]);
        }
        return;
    }
    int work = (flat & 7) * NRT + (flat >> 3);       // bijective XCD chunking (832 = 8*104)
    int rt = work >> 3, ct = work & 7;
    int e = meta[M_RT + rt * 2];
    if (e < 0) return;
    int rowbase = meta[M_RT + rt * 2 + 1];
    int nbase = ct * 64;
    bool shared_tile = (e == NE);

    __shared__ __align__(16) unsigned short As[2][128 * 64];
    __shared__ __align__(16) unsigned short B1s[2][64 * 64];
    __shared__ __align__(16) unsigned short B3s[2][64 * 64];

    int w = tid >> 6, lane = tid & 63;
    int l15 = lane & 15, kq = lane >> 4;
    int wr = w >> 2, wc = w & 3;
    int lr = lane >> 3;
    int lcs = ((lane & 7) ^ lr) << 4;
    int rx = l15 & 7;

    const char* asrc[2];
#pragma unroll
    for (int j = 0; j < 2; j++) {
        int slot = rowbase + j * 64 + w * 8 + lr;
        int tok = shared_tile ? (slot - SHARED_BASE) : row_tok[slot];
        asrc[j] = (const char*)xb + (size_t)tok * (DIM * 2) + lcs;
    }
    const char* B1b = (const char*)(w1b + (size_t)e * HID * DIM + (size_t)nbase * DIM);
    const char* B3b = (const char*)(w3b + (size_t)e * HID * DIM + (size_t)nbase * DIM);

    f32x4 acc1[4], acc3[4];
#pragma unroll
    for (int m = 0; m < 4; m++) {
        acc1[m] = (f32x4){0.f, 0.f, 0.f, 0.f};
        acc3[m] = (f32x4){0.f, 0.f, 0.f, 0.f};
    }

    auto STAGE = [&](int b, int k0) {                 // 4 issues per wave
#pragma unroll
        for (int j = 0; j < 2; j++) {
            int r0 = j * 64 + w * 8;
            gload_lds16(asrc[j] + k0 * 2, (char*)As[b] + r0 * 128);
        }
        int r0 = w * 8;
        gload_lds16(B1b + (size_t)(r0 + lr) * (DIM * 2) + k0 * 2 + lcs,
                    (char*)B1s[b] + r0 * 128);
        gload_lds16(B3b + (size_t)(r0 + lr) * (DIM * 2) + k0 * 2 + lcs,
                    (char*)B3s[b] + r0 * 128);
    };

    STAGE(0, 0);
#pragma unroll 1
    for (int t = 0; t < 16; t++) {
        int cur = t & 1;
        if (t < 15) {
            STAGE(cur ^ 1, (t + 1) * 64);
            asm volatile("s_waitcnt vmcnt(4)" ::: "memory");
        } else {
            asm volatile("s_waitcnt vmcnt(0)" ::: "memory");
        }
        __builtin_amdgcn_sched_barrier(0);
        __builtin_amdgcn_s_barrier();
        __builtin_amdgcn_sched_barrier(0);
#pragma unroll
        for (int kk = 0; kk < 64; kk += 32) {
            int sl = kq + (kk >> 3);
            s16x8 af[4], b1f, b3f;
#pragma unroll
            for (int m = 0; m < 4; m++)
                af[m] = *(const s16x8*)&As[cur][(wr * 64 + m * 16 + l15) * 64 + ((sl ^ rx) << 3)];
            b1f = *(const s16x8*)&B1s[cur][(wc * 16 + l15) * 64 + ((sl ^ rx) << 3)];
            b3f = *(const s16x8*)&B3s[cur][(wc * 16 + l15) * 64 + ((sl ^ rx) << 3)];
#pragma unroll
            for (int m = 0; m < 4; m++) {
                acc1[m] = __builtin_amdgcn_mfma_f32_16x16x32_bf16(af[m], b1f, acc1[m], 0, 0, 0);
                acc3[m] = __builtin_amdgcn_mfma_f32_16x16x32_bf16(af[m], b3f, acc3[m], 0, 0, 0);
            }
        }
        __builtin_amdgcn_sched_barrier(0);
        __builtin_amdgcn_s_barrier();
    }
#pragma unroll
    for (int m = 0; m < 4; m++)
#pragma unroll
        for (int i = 0; i < 4; i++) {
            int row = rowbase + wr * 64 + m * 16 + kq * 4 + i;
            float sc = shared_tile ? 1.f : row_sc[row];
            float h1 = sc * acc1[m][i], h3 = sc * acc3[m][i];
            float gv = h1 / (1.f + expf(-h1)) * h3;
            int col = nbase + wc * 16 + l15;
            g[(size_t)row * HID + col] = f2bf(gv);
        }
}

// ---------------- GEMM2: 128x128 tile, BK=64, 512 threads (8 waves), y = g W2^T ----------------
__global__ __launch_bounds__(512) void k_gemm2(const unsigned short* __restrict__ g,
                                               const unsigned short* __restrict__ w2b,
                                               const int* __restrict__ meta,
                                               unsigned short* __restrict__ y) {
    int flat = blockIdx.y * NRT + blockIdx.x;
    int work = (flat & 7) * NRT + (flat >> 3);
    int rt = work >> 3, ct = work & 7;
    int e = meta[M_RT + rt * 2];
    if (e < 0) return;
    int rowbase = meta[M_RT + rt * 2 + 1];
    int nbase = ct * 128;

    __shared__ __align__(16) unsigned short As[2][128 * 64];
    __shared__ __align__(16) unsigned short Bs[2][128 * 64];

    int tid = threadIdx.x, w = tid >> 6, lane = tid & 63;
    int l15 = lane & 15, kq = lane >> 4;
    int wr = w >> 2, wc = w & 3;
    int lr = lane >> 3;
    int lcs = ((lane & 7) ^ lr) << 4;
    int rx = l15 & 7;

    const char* Ab = (const char*)(g + (size_t)rowbase * HID);
    const char* Bb = (const char*)(w2b + (size_t)e * DIM * HID + (size_t)nbase * HID);

    f32x4 acc[4][2];
#pragma unroll
    for (int m = 0; m < 4; m++)
#pragma unroll
        for (int n = 0; n < 2; n++) acc[m][n] = (f32x4){0.f, 0.f, 0.f, 0.f};

    auto STAGE = [&](int b, int k0) {
#pragma unroll
        for (int j = 0; j < 2; j++) {
            int r0 = j * 64 + w * 8;
            gload_lds16(Ab + (size_t)(r0 + lr) * (HID * 2) + k0 * 2 + lcs,
                        (char*)As[b] + r0 * 128);
            gload_lds16(Bb + (size_t)(r0 + lr) * (HID * 2) + k0 * 2 + lcs,
                        (char*)Bs[b] + r0 * 128);
        }
    };

    STAGE(0, 0);
#pragma unroll 1
    for (int t = 0; t < 8; t++) {
        int cur = t & 1;
        if (t < 7) {
            STAGE(cur ^ 1, (t + 1) * 64);
            asm volatile("s_waitcnt vmcnt(4)" ::: "memory");
        } else {
            asm volatile("s_waitcnt vmcnt(0)" ::: "memory");
        }
        __builtin_amdgcn_sched_barrier(0);
        __builtin_amdgcn_s_barrier();
        __builtin_amdgcn_sched_barrier(0);
#pragma unroll
        for (int kk = 0; kk < 64; kk += 32) {
            int sl = kq + (kk >> 3);
            s16x8 af[4], bf[2];
#pragma unroll
            for (int m = 0; m < 4; m++)
                af[m] = *(const s16x8*)&As[cur][(wr * 64 + m * 16 + l15) * 64 + ((sl ^ rx) << 3)];
#pragma unroll
            for (int n = 0; n < 2; n++)
                bf[n] = *(const s16x8*)&Bs[cur][(wc * 32 + n * 16 + l15) * 64 + ((sl ^ rx) << 3)];
#pragma unroll
            for (int m = 0; m < 4; m++)
#pragma unroll
                for (int n = 0; n < 2; n++)
                    acc[m][n] = __builtin_amdgcn_mfma_f32_16x16x32_bf16(af[m], bf[n], acc[m][n], 0, 0, 0);
        }
        __builtin_amdgcn_sched_barrier(0);
        __builtin_amdgcn_s_barrier();
    }
#pragma unroll
    for (int m = 0; m < 4; m++)
#pragma unroll
        for (int n = 0; n < 2; n++)
#pragma unroll
            for (int i = 0; i < 4; i++) {
                int row = rowbase + wr * 64 + m * 16 + kq * 4 + i;
                int col = nbase + wc * 32 + n * 16 + l15;
                y[(size_t)row * DIM + col] = f2bf(acc[m][n][i]);
            }
}

// ---------------- combine: out[t] = y[s0]+y[s1]+y[shared+t] (fp32 out) ----------------
__global__ __launch_bounds__(256) void k_combine(const unsigned short* __restrict__ y,
                                                 const int* __restrict__ slot_of,
                                                 float* __restrict__ out) {
    int idx = blockIdx.x * 256 + threadIdx.x;
    int t = idx >> 7;
    int d = (idx & 127) << 3;
    int s0 = slot_of[2 * t], s1 = slot_of[2 * t + 1];
    s16x8 a = *(const s16x8*)&y[(size_t)s0 * DIM + d];
    s16x8 b = *(const s16x8*)&y[(size_t)s1 * DIM + d];
    s16x8 c = *(const s16x8*)&y[(size_t)(SHARED_BASE + t) * DIM + d];
    f32x4 o0, o1;
#pragma unroll
    for (int i = 0; i < 4; i++) {
        o0[i] = bf2f((unsigned short)a[i]) + bf2f((unsigned short)b[i]) + bf2f((unsigned short)c[i]);
        o1[i] = bf2f((unsigned short)a[i + 4]) + bf2f((unsigned short)b[i + 4]) + bf2f((unsigned short)c[i + 4]);
    }
    *(f32x4*)&out[(size_t)t * DIM + d + 0] = o0;
    *(f32x4*)&out[(size_t)t * DIM + d + 4] = o1;
}

extern "C" void kernel_launch(void* const* d_in, const int* in_sizes, int n_in,
                              void* d_out, int out_size, void* d_ws, size_t ws_size,
                              hipStream_t stream) {
    const float* x   = (const float*)d_in[0];
    const float* gw  = (const float*)d_in[1];
    const float* w1  = (const float*)d_in[2];
    const float* w2  = (const float*)d_in[3];
    const float* w3  = (const float*)d_in[4];
    const float* sw1 = (const float*)d_in[5];
    const float* sw2 = (const float*)d_in[6];
    const float* sw3 = (const float*)d_in[7];
    float* out = (float*)d_out;

    char* ws = (char*)d_ws;
    size_t off = 0;
    unsigned short* W1B = (unsigned short*)(ws + off); off += (size_t)9 * HID * DIM * 2;
    unsigned short* W3B = (unsigned short*)(ws + off); off += (size_t)9 * HID * DIM * 2;
    unsigned short* W2B = (unsigned short*)(ws + off); off += (size_t)9 * DIM * HID * 2;
    unsigned short* A1  = (unsigned short*)(ws + off); off += (size_t)TOTAL_SLOTS * DIM * 2;
    unsigned short* G   = (unsigned short*)(ws + off); off += (size_t)TOTAL_SLOTS * HID * 2;
    unsigned short* Y   = A1;
    unsigned short* XB  = A1 + (size_t)SHARED_BASE * DIM;
    int*   TOPE = (int*)(ws + off);   off += T_TOK * 2 * 4;
    float* TOPS = (float*)(ws + off); off += T_TOK * 2 * 4;
    int*   SLOT = (int*)(ws + off);   off += T_TOK * 2 * 4;
    int*   RTOK = (int*)(ws + off);   off += TOTAL_SLOTS * 4;
    float* RSC  = (float*)(ws + off); off += TOTAL_SLOTS * 4;
    int*   META = (int*)(ws + off);   off += 1024;

    // fused front: gate (emits xb too) || w1/w3 -> bf16
    k_front<<<FRONT_GATE + FRONT_CONV, 256, 0, stream>>>(x, gw, w1, sw1, w3, sw3,
                                                         W1B, XB, TOPE, TOPS);
    k_route<<<1, 256, 0, stream>>>(TOPE, TOPS, META, SLOT, RTOK, RSC);

    // gemm1 (832 blocks) || w2 conversion (128 blocks)
    k_gemm1<<<G1_BLOCKS + W2CONV_BLOCKS, 512, 0, stream>>>(XB, W1B, W3B, META, RTOK, RSC, G,
                                                           w2, sw2, W2B);
    k_gemm2<<<dim3(NRT, 8, 1), 512, 0, stream>>>(G, W2B, META, Y);

    k_combine<<<(T_TOK * DIM / 8) / 256, 256, 0, stream>>>(Y, SLOT, out);
}